// Round 1
// baseline (264.674 us; speedup 1.0000x reference)
//
#include <hip/hip_runtime.h>
#include <string.h>

#define ALPHA 0.2f
// B=128, L=512, FIN=FOUT=128. Global I/O fp32; internal GEMMs bf16 MFMA.

typedef short short8 __attribute__((ext_vector_type(8)));
typedef float floatx4 __attribute__((ext_vector_type(4)));
typedef int intx4 __attribute__((ext_vector_type(4)));
typedef unsigned short ushort4v __attribute__((ext_vector_type(4)));

__device__ inline unsigned short f2bf(float f) {
    unsigned int v; __builtin_memcpy(&v, &f, 4);
    v = v + 0x7FFFu + ((v >> 16) & 1u);   // RNE
    return (unsigned short)(v >> 16);
}

__device__ inline floatx4 ntload_f4(const float* p) {
    return __builtin_nontemporal_load((const floatx4*)p);
}

// ---------------------------------------------------------------------------
// Kernel 1: Wh^T = (h @ W)^T via swapped MFMA operands (A=W^T rows=o, B=h rows=j)
// C/D tile natively [o][j]. Emits ei/ej from fp32 accumulators.
// 512 threads/block (8 waves), grid 512. LDS 70.7KB -> 2 blk/CU = 16 waves/CU.
// ---------------------------------------------------------------------------
__global__ __launch_bounds__(512, 4) void wh_kernel(const float* __restrict__ h,
                                                    const float* __restrict__ W,
                                                    const float* __restrict__ a,
                                                    unsigned short* __restrict__ wht,
                                                    float* __restrict__ ei,
                                                    float* __restrict__ ej)
{
    __shared__ __align__(16) unsigned short h_s[128][136];  // [j_local][f] bf16
    __shared__ __align__(16) unsigned short w_s[128][136];  // [o][f] bf16
    __shared__ float a_s[256];
    const int tid  = threadIdx.x;
    const int lane = tid & 63;
    const int wv   = tid >> 6;        // 0..7
    const int quad = lane >> 4;
    const int l16  = lane & 15;
    const int r0   = blockIdx.x * 128;
    const int b    = r0 >> 9;
    const int jb   = r0 & 511;

    const float* hbase = h + (size_t)r0 * 128;
#pragma unroll
    for (int it = 0; it < 8; ++it) {
        int idx4 = it * 512 + tid;               // 4096 float4 chunks
        floatx4 v = ntload_f4(hbase + idx4 * 4); // h read exactly once -> nt
        int row = idx4 >> 5;
        int col = (idx4 & 31) * 4;
        ushort4v u;
        for (int e = 0; e < 4; ++e) u[e] = f2bf(v[e]);
        *(ushort4v*)&h_s[row][col] = u;
    }
#pragma unroll
    for (int it = 0; it < 32; ++it) {
        int idx = it * 512 + tid;
        w_s[idx & 127][idx >> 7] = f2bf(W[idx]);
    }
    if (tid < 256) a_s[tid] = a[tid];
    __syncthreads();

    floatx4 acc[8];
#pragma unroll
    for (int mo = 0; mo < 8; ++mo) acc[mo] = (floatx4)0.f;

#pragma unroll
    for (int kk = 0; kk < 4; ++kk) {
        short8 bfr = *(const short8*)&h_s[wv * 16 + l16][kk * 32 + quad * 8];
#pragma unroll
        for (int mo = 0; mo < 8; ++mo) {
            short8 afr = *(const short8*)&w_s[mo * 16 + l16][kk * 32 + quad * 8];
            acc[mo] = __builtin_amdgcn_mfma_f32_16x16x32_bf16(afr, bfr, acc[mo], 0, 0, 0);
        }
    }

    // ei/ej from fp32 accumulators (dot with a[:128] / a[128:])
    {
        float si = 0.f, sj = 0.f;
#pragma unroll
        for (int mo = 0; mo < 8; ++mo)
            for (int r = 0; r < 4; ++r) {
                int o = mo * 16 + quad * 4 + r;
                float v = acc[mo][r];
                si += v * a_s[o];
                sj += v * a_s[128 + o];
            }
        si += __shfl_xor(si, 16); si += __shfl_xor(si, 32);
        sj += __shfl_xor(sj, 16); sj += __shfl_xor(sj, 32);
        if (quad == 0) {
            int j = jb + wv * 16 + l16;
            ei[b * 512 + j] = si;
            ej[b * 512 + j] = sj;
        }
    }

#pragma unroll
    for (int mo = 0; mo < 8; ++mo)
        for (int r = 0; r < 4; ++r) {
            int o = mo * 16 + quad * 4 + r;
            int j = jb + wv * 16 + l16;
            wht[(size_t)b * 65536 + o * 512 + j] = f2bf(acc[mo][r]);
        }
}

// ---------------------------------------------------------------------------
// Kernel 2: scores -> softmax (no max-sub, deferred sums) -> att @ Wh -> elu.
// One block per (b, 32-row i-tile): grid 2048 x 512 threads (8 waves).
// LDS 33.8KB -> 4 blk/CU x 8 waves = 32 waves/CU (was 16).
// ---------------------------------------------------------------------------
__global__ __launch_bounds__(512, 8) void attn_kernel(const unsigned short* __restrict__ wht,
                                                      const float* __restrict__ ei,
                                                      const float* __restrict__ ej,
                                                      const float* __restrict__ bias,
                                                      const int* __restrict__ adj,
                                                      float* __restrict__ out)
{
    __shared__ __align__(16) unsigned short p_s[32][520];    // unnormalized probs
    __shared__ float ei_s[32];
    __shared__ float s_row[32];

    const int tid  = threadIdx.x;
    const int lane = tid & 63;
    const int wv   = tid >> 6;        // 0..7
    const int quad = lane >> 4;
    const int l16  = lane & 15;
    const int b    = blockIdx.x >> 4;
    const int i0   = (blockIdx.x & 15) * 32;

    // Issue row-0 bias/adj loads before the barrier (latency hiding).
    const float* bp = bias + ((size_t)(b * 512 + i0 + wv * 4)) * 512;
    const int*   ap = adj + (i0 + wv * 4) * 512;
    floatx4 bb0 = ntload_f4(bp + lane * 4);          // bias streamed once -> nt
    floatx4 bb1 = ntload_f4(bp + 256 + lane * 4);
    intx4   mm0 = *(const intx4*)(ap + lane * 4);    // adj reused across b -> cached
    intx4   mm1 = *(const intx4*)(ap + 256 + lane * 4);

    const floatx4 ejv0 = *(const floatx4*)(ej + b * 512 + lane * 4);
    const floatx4 ejv1 = *(const floatx4*)(ej + b * 512 + 256 + lane * 4);
    if (tid < 32) ei_s[tid] = ei[b * 512 + i0 + tid];
    __syncthreads();

    // ---- Phase A: one wave per 4 rows; depth-1 prefetch ----
    float rsum[4];

#pragma unroll
    for (int rr = 0; rr < 4; ++rr) {
        floatx4 nb0, nb1; intx4 nm0, nm1;
        if (rr < 3) {                              // prefetch next row
            nb0 = ntload_f4(bp + 512 + lane * 4);
            nb1 = ntload_f4(bp + 768 + lane * 4);
            nm0 = *(const intx4*)(ap + 512 + lane * 4);
            nm1 = *(const intx4*)(ap + 768 + lane * 4);
        }
        const int il = wv * 4 + rr;
        const float eiv = ei_s[il];
        float sm = 0.f;
        ushort4v p0, p1;
        for (int e = 0; e < 4; ++e) {
            float x = eiv + ejv0[e];
            x = fmaxf(x, ALPHA * x);               // leaky relu (1 max)
            x += bb0[e];
            float p = __expf(x);                   // no max-subtraction (|x| small)
            p = (mm0[e] != 0) ? p : 0.f;
            sm += p;
            p0[e] = f2bf(p);
        }
        for (int e = 0; e < 4; ++e) {
            float x = eiv + ejv1[e];
            x = fmaxf(x, ALPHA * x);
            x += bb1[e];
            float p = __expf(x);
            p = (mm1[e] != 0) ? p : 0.f;
            sm += p;
            p1[e] = f2bf(p);
        }
        *(ushort4v*)&p_s[il][lane * 4]       = p0;
        *(ushort4v*)&p_s[il][256 + lane * 4] = p1;
        rsum[rr] = sm;
        bb0 = nb0; bb1 = nb1; mm0 = nm0; mm1 = nm1;
        bp += 512; ap += 512;
    }

    // Prime Phase-B B-frag stream while reductions run.
    const unsigned short* wb = wht + (size_t)b * 65536 + (wv * 16 + l16) * 512 + quad * 8;
    short8 bf = *(const short8*)(wb);

    // Deferred row-sum reductions: 4 independent trees, pipelined
#pragma unroll
    for (int rr = 0; rr < 4; ++rr)
        for (int off = 32; off; off >>= 1)
            rsum[rr] += __shfl_xor(rsum[rr], off);
    if (lane == 0)
#pragma unroll
        for (int rr = 0; rr < 4; ++rr) s_row[wv * 4 + rr] = rsum[rr];
    __syncthreads();

    // ---- Phase B: C[32x16] per wave = P[32x512] @ Wh[512x16-slice], B-frags from L2 ----
    floatx4 acc[2];
    acc[0] = (floatx4)0.f;
    acc[1] = (floatx4)0.f;

#pragma unroll
    for (int k16 = 0; k16 < 16; ++k16) {
        int ko = k16 * 32 + quad * 8;
        short8 nbf;
        if (k16 < 15) nbf = *(const short8*)(wb + (k16 + 1) * 32);
        short8 af0 = *(const short8*)&p_s[l16][ko];
        short8 af1 = *(const short8*)&p_s[16 + l16][ko];
        acc[0] = __builtin_amdgcn_mfma_f32_16x16x32_bf16(af0, bf, acc[0], 0, 0, 0);
        acc[1] = __builtin_amdgcn_mfma_f32_16x16x32_bf16(af1, bf, acc[1], 0, 0, 0);
        bf = nbf;
    }

    // ---- Epilogue: normalize, elu, fp32 nontemporal store ----
#pragma unroll
    for (int m = 0; m < 2; ++m)
        for (int r = 0; r < 4; ++r) {
            int il = m * 16 + quad * 4 + r;
            int o  = wv * 16 + l16;
            float v = acc[m][r] / s_row[il];
            v = v > 0.f ? v : (__expf(v) - 1.f);
            __builtin_nontemporal_store(v, &out[((size_t)(b * 512 + i0 + il)) * 128 + o]);
        }
}

// ---------------------------------------------------------------------------
extern "C" void kernel_launch(void* const* d_in, const int* in_sizes, int n_in,
                              void* d_out, int out_size, void* d_ws, size_t ws_size,
                              hipStream_t stream)
{
    const float* h    = (const float*)d_in[0];
    const float* W    = (const float*)d_in[1];
    const float* a    = (const float*)d_in[2];
    const float* bias = (const float*)d_in[3];
    const int*   adj  = (const int*)d_in[4];
    float*       out  = (float*)d_out;

    unsigned short* wht = (unsigned short*)d_ws;          // 16.78 MB bf16 Wh_t[b][o][j]
    float* ei = (float*)((char*)d_ws + 16777216);
    float* ej = ei + 65536;

    hipLaunchKernelGGL(wh_kernel,   dim3(512),  dim3(512), 0, stream, h, W, a, wht, ei, ej);
    hipLaunchKernelGGL(attn_kernel, dim3(2048), dim3(512), 0, stream, wht, ei, ej, bias, adj, out);
}